// Round 1
// baseline (97.532 us; speedup 1.0000x reference)
//
#include <hip/hip_runtime.h>

// DCT2D_Layer: 8x8 block DCT-II (norm=None) + zigzag reorder.
// img [16,3,512,512] f32 -> out [16, 3*64, 64, 64] f32
// v5: v4 read/compute structure (1 block/thread, 16 hoisted float4 loads,
//     768x256 grid) + LDS-staged write transpose:
//     - 8 column phases; each phase stages 8 planes x (4 rows x 64 blocks)
//       in LDS, then each wave writes 1KB-contiguous global_store_dwordx4
//       (2 planes/wave/phase). 16 store instrs/wave @1KB vs 64 @256B.
//     - double-buffered LDS + raw s_barrier + explicit lgkmcnt(0) only:
//       no __syncthreads -> no vmcnt(0) drain -> stores overlap compute.

typedef float f32x4 __attribute__((ext_vector_type(4)));

// 2*cos(m*pi/16)
#define K1 1.9615705608064609f
#define K2 1.8477590650225735f
#define K3 1.6629392246050905f
#define K4 1.4142135623730951f
#define K5 1.1111404660392044f
#define K6 0.7653668647301796f
#define K7 0.3901806440322565f

// Unnormalized DCT-II, factor 2: y[k] = 2*sum_n x[n] cos(pi*(2n+1)k/16)
#define DCT8(x0,x1,x2,x3,x4,x5,x6,x7, y0,y1,y2,y3,y4,y5,y6,y7) do {        \
    float s0=(x0)+(x7), s1=(x1)+(x6), s2=(x2)+(x5), s3=(x3)+(x4);          \
    float d0=(x0)-(x7), d1=(x1)-(x6), d2=(x2)-(x5), d3=(x3)-(x4);          \
    float e0=s0+s3, e1=s1+s2, o0=s0-s3, o1=s1-s2;                          \
    y0 = 2.0f*(e0+e1);                                                     \
    y4 = K4*(e0-e1);                                                       \
    y2 = K2*o0 + K6*o1;                                                    \
    y6 = K6*o0 - K2*o1;                                                    \
    y1 = K1*d0 + K3*d1 + K5*d2 + K7*d3;                                    \
    y3 = K3*d0 - K7*d1 - K1*d2 - K5*d3;                                    \
    y5 = K5*d0 - K1*d1 + K7*d2 + K3*d3;                                    \
    y7 = K7*d0 - K5*d1 + K3*d2 - K1*d3;                                    \
} while (0)

// Hoisted load of row r (two float4 = 32B of this thread's 8x8 block row).
#define LOADROW(r)                                                          \
    const float4 L##r##a = *reinterpret_cast<const float4*>(src + (r)*512); \
    const float4 L##r##b = *reinterpret_cast<const float4*>(src + (r)*512 + 4);

// Row-pass DCT on the already-loaded row r.
#define ROWDCT(r)                                                          \
    DCT8(L##r##a.x,L##r##a.y,L##r##a.z,L##r##a.w,                          \
         L##r##b.x,L##r##b.y,L##r##b.z,L##r##b.w,                          \
         t##r##0,t##r##1,t##r##2,t##r##3,t##r##4,t##r##5,t##r##6,t##r##7);

// One column phase: column v -> 8 zigzag planes (packed as 8x8-bit literal,
// byte u = zigzag plane index of coeff (u, v)).
// Stage in LDS buf[(v&1)], wave-sync with lgkmcnt-only barrier, then each
// wave stores 2 full 1KB-contiguous plane chunks as dwordx4 (nontemporal).
#define COLPHASE(v, PACK) do {                                             \
    float z0,z1,z2,z3,z4,z5,z6,z7;                                         \
    DCT8(t0##v,t1##v,t2##v,t3##v,t4##v,t5##v,t6##v,t7##v,                  \
         z0,z1,z2,z3,z4,z5,z6,z7);                                         \
    float* buf = lds + (((v)&1) << 11);                                    \
    float* w = buf + wr;                                                   \
    w[0]=z0; w[256]=z1; w[512]=z2; w[768]=z3;                              \
    w[1024]=z4; w[1280]=z5; w[1536]=z6; w[1792]=z7;                        \
    asm volatile("s_waitcnt lgkmcnt(0)" ::: "memory");                     \
    __builtin_amdgcn_s_barrier();                                          \
    const f32x4 r0 = *reinterpret_cast<const f32x4*>(buf + (tid << 2));    \
    const f32x4 r1 = *reinterpret_cast<const f32x4*>(buf + 1024 + (tid << 2)); \
    const int p0 = (int)(((PACK) >> (bil*8)) & 63);                        \
    const int p1 = (int)(((PACK) >> (bil*8 + 32)) & 63);                   \
    __builtin_nontemporal_store(r0,                                        \
        reinterpret_cast<f32x4*>(dst + (size_t)p0*4096));                  \
    __builtin_nontemporal_store(r1,                                        \
        reinterpret_cast<f32x4*>(dst + (size_t)p1*4096));                  \
} while (0)

__global__ __launch_bounds__(256) void dct2d_zigzag_kernel(
    const float* __restrict__ img, float* __restrict__ out)
{
    // double-buffered staging: 2 x (8 planes x 4 rows x 64 blocks) = 16KB
    __shared__ float lds[4096];

    const int tid = threadIdx.x;        // 0..255
    const int wg  = blockIdx.x;         // 0..767
    const int bc  = wg >> 4;            // b*3 + ch, 0..47
    const int big = wg & 15;            // group of 4 block-rows
    const int bj  = tid & 63;           // block col (== lane within wave)
    const int bil = tid >> 6;           // local block row 0..3 (== wave id)

    // Input: img[bc, (big*4+bil)*8 + r, bj*8 + x]; channel plane = 512*512
    const float* __restrict__ src =
        img + (size_t)bc * 262144 + (size_t)(big*4 + bil) * 4096 + (size_t)bj * 8;

    // Output chunk base: out[bc*64 + p, big*4 .. big*4+3, :] ; plane = 4096 floats.
    // This thread's float4 slot within the 1KB chunk is bj*4.
    float* __restrict__ dst =
        out + (size_t)bc * 262144 + (size_t)big * 256 + (size_t)bj * 4;

    // LDS write position for the compute phase: slot u stride 256.
    const int wr = bil*64 + bj;

    // Issue all 16 global loads back-to-back: 16KB in flight per wave.
    LOADROW(0) LOADROW(1) LOADROW(2) LOADROW(3)
    LOADROW(4) LOADROW(5) LOADROW(6) LOADROW(7)

    float t00,t01,t02,t03,t04,t05,t06,t07;
    float t10,t11,t12,t13,t14,t15,t16,t17;
    float t20,t21,t22,t23,t24,t25,t26,t27;
    float t30,t31,t32,t33,t34,t35,t36,t37;
    float t40,t41,t42,t43,t44,t45,t46,t47;
    float t50,t51,t52,t53,t54,t55,t56,t57;
    float t60,t61,t62,t63,t64,t65,t66,t67;
    float t70,t71,t72,t73,t74,t75,t76,t77;

    ROWDCT(0) ROWDCT(1) ROWDCT(2) ROWDCT(3)
    ROWDCT(4) ROWDCT(5) ROWDCT(6) ROWDCT(7)

    // Zigzag plane indices per column v, packed byte u = INVZZ[u*8+v].
    COLPHASE(0, 0x2315140A09030200ULL);  // {0,2,3,9,10,20,21,35}
    COLPHASE(1, 0x242216130B080401ULL);  // {1,4,8,11,19,22,34,36}
    COLPHASE(2, 0x30252117120C0705ULL);  // {5,7,12,18,23,33,37,48}
    COLPHASE(3, 0x312F262018110D06ULL);  // {6,13,17,24,32,38,47,49}
    COLPHASE(4, 0x39322E271F19100EULL);  // {14,16,25,31,39,46,50,57}
    COLPHASE(5, 0x3A38332D281E1A0FULL);  // {15,26,30,40,45,51,56,58}
    COLPHASE(6, 0x3E3B37342C291D1BULL);  // {27,29,41,44,52,55,59,62}
    COLPHASE(7, 0x3F3D3C36352B2A1CULL);  // {28,42,43,53,54,60,61,63}
}

extern "C" void kernel_launch(void* const* d_in, const int* in_sizes, int n_in,
                              void* d_out, int out_size, void* d_ws, size_t ws_size,
                              hipStream_t stream)
{
    const float* img = (const float*)d_in[0];
    float* out = (float*)d_out;
    // 196608 threads; 256/block -> 768 workgroups (3 per CU, 12 waves/CU)
    dct2d_zigzag_kernel<<<768, 256, 0, stream>>>(img, out);
}